// Round 9
// baseline (1060.174 us; speedup 1.0000x reference)
//
#include <hip/hip_runtime.h>

#define B_ 1024
#define S_ 64
#define D_ 300
#define DP_ 320
#define H_ 512
#define G3_ 1536
#define Z_ 128
#define NC1 10
#define NC2 16
#define CSTR 64   // dwords per group region (256 B)

typedef __bf16 bf16x8 __attribute__((ext_vector_type(8)));
typedef float f32x4 __attribute__((ext_vector_type(4)));
typedef int i32x4 __attribute__((ext_vector_type(4)));

// cached global->LDS DMA (aux=0)
#define GLLD(g, l) __builtin_amdgcn_global_load_lds( \
    (const __attribute__((address_space(1))) void*)(g), \
    (__attribute__((address_space(3))) void*)(l), 16, 0, 0)
// device-coherent global->LDS DMA: aux=17 = SC0|SC1 -> bypass L1 AND L2,
// served from the device coherence point (placement-independent, r3/r4-proven).
#define GLLD_SYS(g, l) __builtin_amdgcn_global_load_lds( \
    (const __attribute__((address_space(1))) void*)(g), \
    (__attribute__((address_space(3))) void*)(l), 16, 0, 17)

#define MFMA(a, b, c) __builtin_amdgcn_mfma_f32_16x16x32_bf16((a), (b), (c), 0, 0, 0)

// ---------------- prep kernels ----------------
__global__ __launch_bounds__(256) void prep_cnt(unsigned* __restrict__ cnt) {
    int i = blockIdx.x * 256 + threadIdx.x;        // 2048 dwords
    cnt[i] = 0u;
}

// text is [b][s][d]; Xbf re-laid-out to [s][b][dp] so each step's tile is contiguous
__global__ __launch_bounds__(320) void prep_text(const float* __restrict__ text,
                                                 __bf16* __restrict__ Xbf) {
    int bs = blockIdx.x;          // 65536 = B*S, bs = b*S + s
    int b = bs >> 6, s = bs & 63;
    int dp = threadIdx.x;         // 320
    float v = (dp < D_) ? text[(size_t)bs * D_ + dp] : 0.f;
    Xbf[((size_t)s * B_ + b) * DP_ + dp] = (__bf16)v;
}

__global__ __launch_bounds__(256) void prep_w(
    const float* __restrict__ Wih_f, const float* __restrict__ Whh_f,
    const float* __restrict__ Wih_b, const float* __restrict__ Whh_b,
    const float* __restrict__ W_mu, const float* __restrict__ W_sig,
    __bf16* __restrict__ Wk1, __bf16* __restrict__ Wk2, __bf16* __restrict__ Wcat) {
    const int n1 = 2 * G3_ * DP_;       // 983040
    const int n2 = 2 * G3_ * H_;        // 1572864
    int i = blockIdx.x * 256 + threadIdx.x;
    if (i < n1) {
        int dir = i / (G3_ * DP_);
        int rem = i - dir * (G3_ * DP_);
        int r = rem / DP_;
        int k = rem - r * DP_;
        const float* W = dir ? Wih_b : Wih_f;
        Wk1[i] = (k < D_) ? (__bf16)W[(size_t)r * D_ + k] : (__bf16)0.f;
    } else if (i < n1 + n2) {
        int jj = i - n1;
        int dir = jj / (G3_ * H_);
        int rem = jj - dir * (G3_ * H_);
        int r = rem / H_;
        int k = rem - r * H_;
        const float* W = dir ? Whh_b : Whh_f;
        Wk2[jj] = (__bf16)W[(size_t)r * H_ + k];
    } else {
        int idx = i - n1 - n2;          // < 131072
        int z = idx >> 9, k = idx & 511;
        Wcat[idx] = (__bf16)(z < 128 ? W_mu[(size_t)z * H_ + k]
                                     : W_sig[(size_t)(z - 128) * H_ + k]);
    }
}

// ---------------- persistent bidirectional GRU ----------------
// Structure = r7 EXACTLY (proven 658 us steady / 839 us wall): 256 blocks x
// 256 threads, weights register-resident, XOR-swizzled LDS staging (0 bank
// conflicts), 2-deep pipelined fragment reads, bulk h-DMA + single drains,
// AGENT-scope exchange (placement-independent), X(s+1) issued after the
// h-drain. r8's 3-deep + counted-vmcnt split REVOKED (658->681 regression:
// compiler scheduling already covered the LDS latency; extra barriers cost).
// NEW (this round): publish packing. The publish-ack vmcnt(0) waits on the
// LAST of 2048 dword agent stores/block/step (16K acks per group at one
// coherence point). A 3-round shfl tree packs cols j..j+7 into one 16B
// global_store_dwordx4 sc0 sc1 (identical write-through semantics, single
// writer per 128B-aligned slice) -> 512 stores/block, 4x shorter ack tail.
// Also: s=63 publish skipped entirely (h(63) is never consumed).
__global__ __launch_bounds__(256, 1) void gru_persist(
    const __bf16* __restrict__ Xbf, const __bf16* __restrict__ Wk1,
    const __bf16* __restrict__ Wk2,
    const float* __restrict__ bih_f, const float* __restrict__ bhh_f,
    const float* __restrict__ bih_b, const float* __restrict__ bhh_b,
    const int* __restrict__ lens,
    __bf16* __restrict__ Hb0, __bf16* __restrict__ Hb1,
    float* __restrict__ Ssum, unsigned* __restrict__ cnt)
{
    __shared__ __align__(16) __bf16 hbuf[NC2 * 2048];       // 64 KB h staging
    __shared__ __align__(16) __bf16 xbuf[2 * NC1 * 2048];   // 80 KB X double-buffer

    const int bid = blockIdx.x;
    const int xcd = bid & 7, slot = bid >> 3;
    const int dir = xcd >> 2;
    const int mb  = (xcd & 3) * 4 + (slot >> 3);   // 0..15
    const int jb  = slot & 7;                      // 0..7
    const int b0  = mb * 64;
    const int group = dir * 16 + mb;
    unsigned* const gcnt = cnt + group * CSTR;

    const int tid = threadIdx.x;
    const int wave = tid >> 6;
    const int lane = tid & 63;

    const int jcol = jb * 64 + wave * 16 + (lane & 15);    // 0..511
    const int kq8  = (lane >> 4) * 8;

    // staging geometry (thread -> row, swizzled col-quad). Thread tid owns LDS
    // slot [row = tid>>2][q_slot = tid&3]; it FETCHES global column
    // q_data = q_slot ^ ((row>>1)&3)  (involution -> reader uses same XOR).
    const int srow = tid >> 2;
    const int scol = ((tid & 3) ^ ((tid >> 3) & 3)) * 8;
    const size_t hrow = (size_t)(dir * B_ + b0 + srow) * H_ + scol;

    // ---- prologue: start X(0) DMA first so it overlaps the weight loads ----
    {
        const int sx0 = dir ? (S_ - 1) : 0;
        const __bf16* src = Xbf + ((size_t)sx0 * B_ + b0 + srow) * DP_ + scol;
        __bf16* dst = xbuf + wave * 512;          // wave-uniform + lane*16B
#pragma unroll
        for (int c = 0; c < NC1; ++c)
            GLLD(src + c * 32, dst + c * 2048);
    }

    // ---- one-time: load BOTH weight slices into registers ----
    bf16x8 w1c[NC1][3];   // Wih fragments
    bf16x8 w2c[NC2][3];   // Whh fragments
    {
        const __bf16* w1p[3];
        const __bf16* w2p[3];
#pragma unroll
        for (int g = 0; g < 3; ++g) {
            w1p[g] = Wk1 + ((size_t)dir * G3_ + g * H_ + jcol) * DP_ + kq8;
            w2p[g] = Wk2 + ((size_t)dir * G3_ + g * H_ + jcol) * H_ + kq8;
        }
#pragma unroll
        for (int c = 0; c < NC1; ++c)
#pragma unroll
            for (int g = 0; g < 3; ++g)
                w1c[c][g] = *(const bf16x8*)(w1p[g] + c * 32);
#pragma unroll
        for (int c = 0; c < NC2; ++c)
#pragma unroll
            for (int g = 0; g < 3; ++g)
                w2c[c][g] = *(const bf16x8*)(w2p[g] + c * 32);
    }

    const float* bih = dir ? bih_b : bih_f;
    const float* bhh = dir ? bhh_b : bhh_f;
    const float b_r  = bih[jcol] + bhh[jcol];
    const float b_z  = bih[H_ + jcol] + bhh[H_ + jcol];
    const float b_ni = bih[2 * H_ + jcol];
    const float b_nh = bhh[2 * H_ + jcol];

    unsigned lenp[4];
#pragma unroll
    for (int mt = 0; mt < 4; ++mt) {
        int r0 = b0 + mt * 16 + (lane >> 4) * 4;
        lenp[mt] = (unsigned)(lens[r0] & 255) | ((unsigned)(lens[r0 + 1] & 255) << 8)
                 | ((unsigned)(lens[r0 + 2] & 255) << 16) | ((unsigned)(lens[r0 + 3] & 255) << 24);
    }

    float hreg[16], ssum[16];
#pragma unroll
    for (int i = 0; i < 16; ++i) { hreg[i] = 0.f; ssum[i] = 0.f; }

    // swizzled fragment read offset: row = mt*16+(lane&15), data-quad = lane>>4
    // -> slot-quad = (lane>>4) ^ ((row>>1)&3); mt*16 doesn't touch bits [2:1].
    const int qsl  = (lane >> 4) ^ ((lane >> 1) & 3);
    const int aoff = (lane & 15) * 32 + qsl * 8;

    // packed-publish geometry: lanes with (lane&7)==0 store 16B covering
    // cols jcol..jcol+7 (jcol multiple of 8 there -> 16B-aligned).
    const bool pub_lane = (lane & 7) == 0;

// fragment load / MFMA macros (all indices compile-time after unroll)
#define LDX(P, c) do { _Pragma("unroll") \
    for (int mt_ = 0; mt_ < 4; ++mt_) \
        P[mt_] = *(const bf16x8*)(xb + (c) * 2048 + aoff + mt_ * 512); } while (0)
#define LDH(P, c) do { _Pragma("unroll") \
    for (int mt_ = 0; mt_ < 4; ++mt_) \
        P[mt_] = *(const bf16x8*)(hbuf + (c) * 2048 + aoff + mt_ * 512); } while (0)
#define FMA1(P, c) do { _Pragma("unroll") \
    for (int mt_ = 0; mt_ < 4; ++mt_) { \
        acc[mt_][0] = MFMA(P[mt_], w1c[c][0], acc[mt_][0]); \
        acc[mt_][1] = MFMA(P[mt_], w1c[c][1], acc[mt_][1]); \
        acc[mt_][2] = MFMA(P[mt_], w1c[c][2], acc[mt_][2]); } } while (0)
#define FMA2(P, c) do { _Pragma("unroll") \
    for (int mt_ = 0; mt_ < 4; ++mt_) { \
        acc[mt_][0] = MFMA(P[mt_], w2c[c][0], acc[mt_][0]); \
        acc[mt_][1] = MFMA(P[mt_], w2c[c][1], acc[mt_][1]); \
        acc[mt_][3] = MFMA(P[mt_], w2c[c][2], acc[mt_][3]); } } while (0)
// X(s+1) prefetch issue (10 cached GLLDs into the other xbuf half)
#define XDMA(snext) do { \
    const int sxn_ = dir ? (S_ - 1 - (snext)) : (snext); \
    const __bf16* src_ = Xbf + ((size_t)sxn_ * B_ + b0 + srow) * DP_ + scol; \
    __bf16* dst_ = xbuf + ((snext) & 1) * (NC1 * 2048) + wave * 512; \
    _Pragma("unroll") \
    for (int c_ = 0; c_ < NC1; ++c_) \
        GLLD(src_ + c_ * 32, dst_ + c_ * 2048); } while (0)

    // drain X(0) DMA (vmcnt(0) implied) before phase 1 reads xbuf[0]
    __syncthreads();

    for (int s = 0; s < S_; ++s) {
        // s==0 has no mid-step barriers: issue X(1) at step top (max cover).
        if (s == 0) XDMA(1);

        f32x4 acc[4][4];
#pragma unroll
        for (int mt = 0; mt < 4; ++mt)
#pragma unroll
            for (int p = 0; p < 4; ++p)
                acc[mt][p] = (f32x4){0.f, 0.f, 0.f, 0.f};

        const __bf16* xb = xbuf + (s & 1) * (NC1 * 2048);
        bf16x8 pa[4], pb[4];

        // ---- phase 1a: chunks 0..3 pipelined (slack for peer skew) ----
        LDX(pa, 0); LDX(pb, 1);
        FMA1(pa, 0); LDX(pa, 2);
        FMA1(pb, 1); LDX(pb, 3);
        FMA1(pa, 2); LDX(pa, 4);
        FMA1(pb, 3); LDX(pb, 5);

        if (s > 0) {
            // ---- wait for group peers: AGENT-scope poll (placement-independent) ----
            if (tid == 0) {
                const unsigned tgt = 8u * (unsigned)s;
                unsigned it = 0;
                while (__hip_atomic_load(gcnt, __ATOMIC_RELAXED,
                                         __HIP_MEMORY_SCOPE_AGENT) < tgt) {
                    if (++it > (1u << 20)) break;   // hang-safety escape
                }
            }
            __syncthreads();   // cheap: nothing significant outstanding now

            // ---- issue h staging DMA (device-coherent); drained after 1b ----
            {
                const __bf16* src = ((s & 1) ? Hb1 : Hb0) + hrow;
                __bf16* dst = hbuf + wave * 512;
#pragma unroll
                for (int c = 0; c < NC2; ++c)
                    GLLD_SYS(src + c * 32, dst + c * 2048);
            }
        }

        // ---- phase 1b: chunks 4..9 pipelined (hides the h-DMA round trip) ----
        FMA1(pa, 4); LDX(pa, 6);
        FMA1(pb, 5); LDX(pb, 7);
        FMA1(pa, 6); LDX(pa, 8);
        FMA1(pb, 7); LDX(pb, 9);
        FMA1(pa, 8);
        FMA1(pb, 9);

        if (s > 0) {
            __syncthreads();   // vmcnt(0): drains ONLY the h DMA (X not issued yet)

            // ---- issue X(s+1) now; drains at the post-epilogue barrier,
            //      overlapped with phase 2 + epilogue + publish ack ----
            if (s < S_ - 1) XDMA(s + 1);

            // ---- phase 2: h @ Whh^T, 16 chunks, 2-deep pipelined ----
            LDH(pa, 0); LDH(pb, 1);
#pragma unroll
            for (int cc = 0; cc < 7; ++cc) {
                FMA2(pa, 2 * cc);     LDH(pa, 2 * cc + 2);
                FMA2(pb, 2 * cc + 1); LDH(pb, 2 * cc + 3);
            }
            FMA2(pa, 14);
            FMA2(pb, 15);
        }
        // s == 0: h = 0, so gh = bhh exactly — already folded into b_r/b_z/b_nh.

        // ---- epilogue: GRU cell, reg-resident h & masked sum, packed publish ----
        {
            __bf16* hb_w = (s & 1) ? Hb0 : Hb1;
            const bool do_pub = (s < S_ - 1);   // h(63) never consumed
#pragma unroll
            for (int mt = 0; mt < 4; ++mt) {
#pragma unroll
                for (int reg = 0; reg < 4; ++reg) {
                    const int i = mt * 4 + reg;
                    const float r = 1.f / (1.f + __expf(-(acc[mt][0][reg] + b_r)));
                    const float z = 1.f / (1.f + __expf(-(acc[mt][1][reg] + b_z)));
                    const float nv = acc[mt][2][reg] + b_ni + r * (acc[mt][3][reg] + b_nh);
                    const float n = 2.f / (1.f + __expf(-2.f * nv)) - 1.f;   // tanh
                    const float hnew = (1.f - z) * n + z * hreg[i];
                    hreg[i] = hnew;
                    if (((lenp[mt] >> (reg * 8)) & 255u) > (unsigned)s) ssum[i] += hnew;
                    if (do_pub) {
                        __bf16 hb16 = (__bf16)hnew;
                        unsigned short myb = __builtin_bit_cast(unsigned short, hb16);
                        // round 1: pack col pair (j, j+1) into a dword on even lanes
                        unsigned ob = (unsigned)__shfl_xor((int)(unsigned)myb, 1, 64);
                        unsigned d0 = (unsigned)myb | (ob << 16);
                        // round 2: cols (j+2, j+3) from lane^2
                        unsigned d1 = (unsigned)__shfl_xor((int)d0, 2, 64);
                        // round 3: cols (j+4..j+7) from lane^4
                        unsigned d2 = (unsigned)__shfl_xor((int)d0, 4, 64);
                        unsigned d3 = (unsigned)__shfl_xor((int)d1, 4, 64);
                        if (pub_lane) {
                            const int b = b0 + mt * 16 + (lane >> 4) * 4 + reg;
                            __bf16* p = hb_w + (size_t)(dir * B_ + b) * H_ + jcol;
                            i32x4 v4 = { (int)d0, (int)d1, (int)d2, (int)d3 };
                            // device-coherent 16B store (same sc0|sc1 semantics the
                            // agent atomic stores compiled to; 4x fewer acks).
                            asm volatile(
                                "global_store_dwordx4 %0, %1, off sc0 sc1"
                                :: "v"(p), "v"(v4) : "memory");
                        }
                    }
                }
            }
        }
        __syncthreads();   // vmcnt(0): publish stores acked; X(s+1) drained
        if (tid == 0 && s < S_ - 1)
            __hip_atomic_fetch_add(gcnt, 1u, __ATOMIC_RELAXED,
                                   __HIP_MEMORY_SCOPE_AGENT);
    }

#undef LDX
#undef LDH
#undef FMA1
#undef FMA2
#undef XDMA

    // write masked sums (consumed by next kernel; dispatch-boundary flush)
#pragma unroll
    for (int mt = 0; mt < 4; ++mt)
#pragma unroll
        for (int reg = 0; reg < 4; ++reg) {
            const int b = b0 + mt * 16 + (lane >> 4) * 4 + reg;
            Ssum[(size_t)(dir * B_ + b) * H_ + jcol] = ssum[mt * 4 + reg];
        }
}

// ---------------- head ----------------
__global__ __launch_bounds__(128) void avg_prep(const float* __restrict__ Ssum,
                                                const int* __restrict__ lens,
                                                __bf16* __restrict__ Avg) {
    int b = blockIdx.x, t = threadIdx.x;
    float inv = 0.5f / (float)lens[b];
    float4 a = *(const float4*)(Ssum + (size_t)b * H_ + t * 4);
    float4 c = *(const float4*)(Ssum + (size_t)(B_ + b) * H_ + t * 4);
    __bf16* dst = Avg + (size_t)b * H_ + t * 4;
    dst[0] = (__bf16)((a.x + c.x) * inv);
    dst[1] = (__bf16)((a.y + c.y) * inv);
    dst[2] = (__bf16)((a.z + c.z) * inv);
    dst[3] = (__bf16)((a.w + c.w) * inv);
}

// Avg[1024x512] @ Wcat[256x512]^T -> mu/sigma planes of out
__global__ __launch_bounds__(256) void head_gemm(
    const __bf16* __restrict__ Avg, const __bf16* __restrict__ Wcat,
    const float* __restrict__ b_mu, const float* __restrict__ b_sig,
    float* __restrict__ out)
{
    __shared__ __align__(16) __bf16 abuf[16 * 2048];   // 64 KB static
    const int bid = blockIdx.x;                        // 64
    const int mb = bid >> 2, jb = bid & 3;
    const int tid = threadIdx.x, wave = tid >> 6, lane = tid & 63;
    const int srow = tid >> 2, scol = (tid & 3) * 8;
    const __bf16* asrc = Avg + (size_t)(mb * 64 + srow) * H_ + scol;
    {
        __bf16* dst = abuf + wave * 512;
#pragma unroll
        for (int c = 0; c < 16; ++c) GLLD(asrc + c * 32, dst + c * 2048);
    }
    __syncthreads();
    const int j = jb * 64 + wave * 16 + (lane & 15);   // 0..255
    const int kq8 = (lane >> 4) * 8;
    const __bf16* wp = Wcat + (size_t)j * H_ + kq8;
    const int aoff = (lane & 15) * 32 + kq8;
    f32x4 acc[4];
#pragma unroll
    for (int mt = 0; mt < 4; ++mt) acc[mt] = (f32x4){0.f, 0.f, 0.f, 0.f};
#pragma unroll
    for (int c = 0; c < 16; ++c) {
        bf16x8 wf = *(const bf16x8*)(wp + c * 32);
#pragma unroll
        for (int mt = 0; mt < 4; ++mt) {
            bf16x8 af = *(const bf16x8*)(abuf + c * 2048 + aoff + mt * 512);
            acc[mt] = MFMA(af, wf, acc[mt]);
        }
    }
    const int gate = j >> 7, z = j & 127;
    const float bias = gate ? b_sig[z] : b_mu[z];
#pragma unroll
    for (int mt = 0; mt < 4; ++mt)
#pragma unroll
        for (int reg = 0; reg < 4; ++reg) {
            const int b = mb * 64 + mt * 16 + (lane >> 4) * 4 + reg;
            float v = acc[mt][reg] + bias;
            v = v >= 0.f ? v : 0.2f * v;
            if (gate) v = __expf(v);
            out[(size_t)(1 + gate) * B_ * Z_ + (size_t)b * Z_ + z] = v;
        }
}

__global__ __launch_bounds__(256) void final_k(const float* __restrict__ eps,
                                               float* __restrict__ out) {
    int i = blockIdx.x * 256 + threadIdx.x;    // 131072
    out[i] = eps[i] * out[2 * B_ * Z_ + i] + out[B_ * Z_ + i];
}

extern "C" void kernel_launch(void* const* d_in, const int* in_sizes, int n_in,
                              void* d_out, int out_size, void* d_ws, size_t ws_size,
                              hipStream_t stream) {
    const float* text  = (const float*)d_in[0];
    const int*   lens  = (const int*)  d_in[1];
    const float* Wih_f = (const float*)d_in[2];
    const float* Whh_f = (const float*)d_in[3];
    const float* bih_f = (const float*)d_in[4];
    const float* bhh_f = (const float*)d_in[5];
    const float* Wih_b = (const float*)d_in[6];
    const float* Whh_b = (const float*)d_in[7];
    const float* bih_b = (const float*)d_in[8];
    const float* bhh_b = (const float*)d_in[9];
    const float* W_mu  = (const float*)d_in[10];
    const float* b_mu  = (const float*)d_in[11];
    const float* W_sig = (const float*)d_in[12];
    const float* b_sig = (const float*)d_in[13];
    const float* eps   = (const float*)d_in[14];
    float* out = (float*)d_out;

    char* ws = (char*)d_ws;
    __bf16* Xbf  = (__bf16*)(ws);                   // 41943040
    __bf16* Wk1  = (__bf16*)(ws + 41943040);        //  1966080
    __bf16* Wk2  = (__bf16*)(ws + 43909120);        //  3145728
    __bf16* Hb0  = (__bf16*)(ws + 47054848);        //  2097152
    __bf16* Hb1  = (__bf16*)(ws + 49152000);        //  2097152
    float*  Ssum = (float*) (ws + 51249152);        //  4194304
    __bf16* Avg  = (__bf16*)(ws + 55443456);        //  1048576
    __bf16* Wcat = (__bf16*)(ws + 56492032);        //   262144
    unsigned* cntp = (unsigned*)(ws + 56754176);    //     8192 (32 groups x 256 B)
    // total 56762368 bytes

    prep_cnt<<<8, 256, 0, stream>>>(cntp);
    prep_text<<<B_ * S_, 320, 0, stream>>>(text, Xbf);
    prep_w<<<10496, 256, 0, stream>>>(Wih_f, Whh_f, Wih_b, Whh_b, W_mu, W_sig,
                                      Wk1, Wk2, Wcat);

    void* args[] = { (void*)&Xbf, (void*)&Wk1, (void*)&Wk2,
                     (void*)&bih_f, (void*)&bhh_f, (void*)&bih_b, (void*)&bhh_b,
                     (void*)&lens, (void*)&Hb0, (void*)&Hb1,
                     (void*)&Ssum, (void*)&cntp };
    hipError_t ce = hipLaunchCooperativeKernel((void*)gru_persist, dim3(256),
                                               dim3(256), args, 0, stream);
    if (ce != hipSuccess) {
        gru_persist<<<256, 256, 0, stream>>>(Xbf, Wk1, Wk2,
                                             bih_f, bhh_f, bih_b, bhh_b,
                                             lens, Hb0, Hb1, Ssum, cntp);
    }

    avg_prep<<<B_, 128, 0, stream>>>(Ssum, lens, Avg);
    head_gemm<<<64, 256, 0, stream>>>(Avg, Wcat, b_mu, b_sig, out);
    final_k<<<512, 256, 0, stream>>>(eps, out);
}

// Round 10
// 835.560 us; speedup vs baseline: 1.2688x; 1.2688x over previous
//
#include <hip/hip_runtime.h>

#define B_ 1024
#define S_ 64
#define D_ 300
#define DP_ 320
#define H_ 512
#define G3_ 1536
#define Z_ 128
#define NC1 10
#define NC2 16
#define CSTR 64   // dwords per group region (256 B)

typedef __bf16 bf16x8 __attribute__((ext_vector_type(8)));
typedef float f32x4 __attribute__((ext_vector_type(4)));

// cached global->LDS DMA (aux=0)
#define GLLD(g, l) __builtin_amdgcn_global_load_lds( \
    (const __attribute__((address_space(1))) void*)(g), \
    (__attribute__((address_space(3))) void*)(l), 16, 0, 0)
// device-coherent global->LDS DMA: aux=17 = SC0|SC1 -> bypass L1 AND L2,
// served from the device coherence point (placement-independent, r3/r4-proven).
#define GLLD_SYS(g, l) __builtin_amdgcn_global_load_lds( \
    (const __attribute__((address_space(1))) void*)(g), \
    (__attribute__((address_space(3))) void*)(l), 16, 0, 17)

#define MFMA(a, b, c) __builtin_amdgcn_mfma_f32_16x16x32_bf16((a), (b), (c), 0, 0, 0)

// ---------------- prep kernels ----------------
__global__ __launch_bounds__(256) void prep_cnt(unsigned* __restrict__ cnt) {
    int i = blockIdx.x * 256 + threadIdx.x;        // 2048 dwords
    cnt[i] = 0u;
}

// text is [b][s][d]; Xbf re-laid-out to [s][b][dp] so each step's tile is contiguous
__global__ __launch_bounds__(320) void prep_text(const float* __restrict__ text,
                                                 __bf16* __restrict__ Xbf) {
    int bs = blockIdx.x;          // 65536 = B*S, bs = b*S + s
    int b = bs >> 6, s = bs & 63;
    int dp = threadIdx.x;         // 320
    float v = (dp < D_) ? text[(size_t)bs * D_ + dp] : 0.f;
    Xbf[((size_t)s * B_ + b) * DP_ + dp] = (__bf16)v;
}

__global__ __launch_bounds__(256) void prep_w(
    const float* __restrict__ Wih_f, const float* __restrict__ Whh_f,
    const float* __restrict__ Wih_b, const float* __restrict__ Whh_b,
    const float* __restrict__ W_mu, const float* __restrict__ W_sig,
    __bf16* __restrict__ Wk1, __bf16* __restrict__ Wk2, __bf16* __restrict__ Wcat) {
    const int n1 = 2 * G3_ * DP_;       // 983040
    const int n2 = 2 * G3_ * H_;        // 1572864
    int i = blockIdx.x * 256 + threadIdx.x;
    if (i < n1) {
        int dir = i / (G3_ * DP_);
        int rem = i - dir * (G3_ * DP_);
        int r = rem / DP_;
        int k = rem - r * DP_;
        const float* W = dir ? Wih_b : Wih_f;
        Wk1[i] = (k < D_) ? (__bf16)W[(size_t)r * D_ + k] : (__bf16)0.f;
    } else if (i < n1 + n2) {
        int jj = i - n1;
        int dir = jj / (G3_ * H_);
        int rem = jj - dir * (G3_ * H_);
        int r = rem / H_;
        int k = rem - r * H_;
        const float* W = dir ? Whh_b : Whh_f;
        Wk2[jj] = (__bf16)W[(size_t)r * H_ + k];
    } else {
        int idx = i - n1 - n2;          // < 131072
        int z = idx >> 9, k = idx & 511;
        Wcat[idx] = (__bf16)(z < 128 ? W_mu[(size_t)z * H_ + k]
                                     : W_sig[(size_t)(z - 128) * H_ + k]);
    }
}

// ---------------- persistent bidirectional GRU ----------------
// FINAL STRUCTURE = r7 verbatim (proven 658 us steady / 839 us wall over the
// r0 baseline's 1127/1317): 256 blocks x 256 threads, weights register-
// resident across all 64 steps, X(s+1) double-buffered via global_load_lds,
// XOR-swizzled LDS staging (bank conflicts 2.7e7 -> 0), 2-deep pipelined
// fragment reads, bulk h-DMA with single drains, AGENT-scope exchange
// (placement-independent), X(s+1) issued after the h-drain point.
// Falsified alternatives (do NOT retry): r5 streamed per-peer exchange
// (poll RTs serialize, -28%); r6 adaptive scope probe (visibility-by-eviction
// makes startup probes unsound -> false L2 verdict -> spin burn); r8 3-deep
// pipeline + counted-vmcnt split (compiler already covers LDS latency;
// barriers cost, -3.5%); r9 packed publish via asm stores (asm "memory"
// fences serialize the epilogue, -36%).
// Only r9 salvage: s=63 publish skipped (h(63) never consumed; wave-uniform
// branch, zero cost).
// Residual stall (~50%) = 64 serial steps x device-coherence round trips
// (publish-ack -> flag -> poll -> h-read, ~2.4 us/RT) — structural, given
// non-coherent per-XCD L2s and launch-path-dependent block placement.
__global__ __launch_bounds__(256, 1) void gru_persist(
    const __bf16* __restrict__ Xbf, const __bf16* __restrict__ Wk1,
    const __bf16* __restrict__ Wk2,
    const float* __restrict__ bih_f, const float* __restrict__ bhh_f,
    const float* __restrict__ bih_b, const float* __restrict__ bhh_b,
    const int* __restrict__ lens,
    __bf16* __restrict__ Hb0, __bf16* __restrict__ Hb1,
    float* __restrict__ Ssum, unsigned* __restrict__ cnt)
{
    __shared__ __align__(16) __bf16 hbuf[NC2 * 2048];       // 64 KB h staging
    __shared__ __align__(16) __bf16 xbuf[2 * NC1 * 2048];   // 80 KB X double-buffer

    const int bid = blockIdx.x;
    const int xcd = bid & 7, slot = bid >> 3;
    const int dir = xcd >> 2;
    const int mb  = (xcd & 3) * 4 + (slot >> 3);   // 0..15
    const int jb  = slot & 7;                      // 0..7
    const int b0  = mb * 64;
    const int group = dir * 16 + mb;
    unsigned* const gcnt = cnt + group * CSTR;

    const int tid = threadIdx.x;
    const int wave = tid >> 6;
    const int lane = tid & 63;

    const int jcol = jb * 64 + wave * 16 + (lane & 15);    // 0..511
    const int kq8  = (lane >> 4) * 8;

    // staging geometry (thread -> row, swizzled col-quad). Thread tid owns LDS
    // slot [row = tid>>2][q_slot = tid&3]; it FETCHES global column
    // q_data = q_slot ^ ((row>>1)&3)  (involution -> reader uses same XOR).
    const int srow = tid >> 2;
    const int scol = ((tid & 3) ^ ((tid >> 3) & 3)) * 8;
    const size_t hrow = (size_t)(dir * B_ + b0 + srow) * H_ + scol;

    // ---- prologue: start X(0) DMA first so it overlaps the weight loads ----
    {
        const int sx0 = dir ? (S_ - 1) : 0;
        const __bf16* src = Xbf + ((size_t)sx0 * B_ + b0 + srow) * DP_ + scol;
        __bf16* dst = xbuf + wave * 512;          // wave-uniform + lane*16B
#pragma unroll
        for (int c = 0; c < NC1; ++c)
            GLLD(src + c * 32, dst + c * 2048);
    }

    // ---- one-time: load BOTH weight slices into registers ----
    bf16x8 w1c[NC1][3];   // Wih fragments
    bf16x8 w2c[NC2][3];   // Whh fragments
    {
        const __bf16* w1p[3];
        const __bf16* w2p[3];
#pragma unroll
        for (int g = 0; g < 3; ++g) {
            w1p[g] = Wk1 + ((size_t)dir * G3_ + g * H_ + jcol) * DP_ + kq8;
            w2p[g] = Wk2 + ((size_t)dir * G3_ + g * H_ + jcol) * H_ + kq8;
        }
#pragma unroll
        for (int c = 0; c < NC1; ++c)
#pragma unroll
            for (int g = 0; g < 3; ++g)
                w1c[c][g] = *(const bf16x8*)(w1p[g] + c * 32);
#pragma unroll
        for (int c = 0; c < NC2; ++c)
#pragma unroll
            for (int g = 0; g < 3; ++g)
                w2c[c][g] = *(const bf16x8*)(w2p[g] + c * 32);
    }

    const float* bih = dir ? bih_b : bih_f;
    const float* bhh = dir ? bhh_b : bhh_f;
    const float b_r  = bih[jcol] + bhh[jcol];
    const float b_z  = bih[H_ + jcol] + bhh[H_ + jcol];
    const float b_ni = bih[2 * H_ + jcol];
    const float b_nh = bhh[2 * H_ + jcol];

    unsigned lenp[4];
#pragma unroll
    for (int mt = 0; mt < 4; ++mt) {
        int r0 = b0 + mt * 16 + (lane >> 4) * 4;
        lenp[mt] = (unsigned)(lens[r0] & 255) | ((unsigned)(lens[r0 + 1] & 255) << 8)
                 | ((unsigned)(lens[r0 + 2] & 255) << 16) | ((unsigned)(lens[r0 + 3] & 255) << 24);
    }

    float hreg[16], ssum[16];
#pragma unroll
    for (int i = 0; i < 16; ++i) { hreg[i] = 0.f; ssum[i] = 0.f; }

    // swizzled fragment read offset: row = mt*16+(lane&15), data-quad = lane>>4
    // -> slot-quad = (lane>>4) ^ ((row>>1)&3); mt*16 doesn't touch bits [2:1].
    const int qsl  = (lane >> 4) ^ ((lane >> 1) & 3);
    const int aoff = (lane & 15) * 32 + qsl * 8;

// fragment load / MFMA macros (all indices compile-time after unroll)
#define LDX(P, c) do { _Pragma("unroll") \
    for (int mt_ = 0; mt_ < 4; ++mt_) \
        P[mt_] = *(const bf16x8*)(xb + (c) * 2048 + aoff + mt_ * 512); } while (0)
#define LDH(P, c) do { _Pragma("unroll") \
    for (int mt_ = 0; mt_ < 4; ++mt_) \
        P[mt_] = *(const bf16x8*)(hbuf + (c) * 2048 + aoff + mt_ * 512); } while (0)
#define FMA1(P, c) do { _Pragma("unroll") \
    for (int mt_ = 0; mt_ < 4; ++mt_) { \
        acc[mt_][0] = MFMA(P[mt_], w1c[c][0], acc[mt_][0]); \
        acc[mt_][1] = MFMA(P[mt_], w1c[c][1], acc[mt_][1]); \
        acc[mt_][2] = MFMA(P[mt_], w1c[c][2], acc[mt_][2]); } } while (0)
#define FMA2(P, c) do { _Pragma("unroll") \
    for (int mt_ = 0; mt_ < 4; ++mt_) { \
        acc[mt_][0] = MFMA(P[mt_], w2c[c][0], acc[mt_][0]); \
        acc[mt_][1] = MFMA(P[mt_], w2c[c][1], acc[mt_][1]); \
        acc[mt_][3] = MFMA(P[mt_], w2c[c][2], acc[mt_][3]); } } while (0)
// X(s+1) prefetch issue (10 cached GLLDs into the other xbuf half)
#define XDMA(snext) do { \
    const int sxn_ = dir ? (S_ - 1 - (snext)) : (snext); \
    const __bf16* src_ = Xbf + ((size_t)sxn_ * B_ + b0 + srow) * DP_ + scol; \
    __bf16* dst_ = xbuf + ((snext) & 1) * (NC1 * 2048) + wave * 512; \
    _Pragma("unroll") \
    for (int c_ = 0; c_ < NC1; ++c_) \
        GLLD(src_ + c_ * 32, dst_ + c_ * 2048); } while (0)

    // drain X(0) DMA (vmcnt(0) implied) before phase 1 reads xbuf[0]
    __syncthreads();

    for (int s = 0; s < S_; ++s) {
        // s==0 has no mid-step barriers: issue X(1) at step top (max cover).
        if (s == 0) XDMA(1);

        f32x4 acc[4][4];
#pragma unroll
        for (int mt = 0; mt < 4; ++mt)
#pragma unroll
            for (int p = 0; p < 4; ++p)
                acc[mt][p] = (f32x4){0.f, 0.f, 0.f, 0.f};

        const __bf16* xb = xbuf + (s & 1) * (NC1 * 2048);
        bf16x8 pa[4], pb[4];

        // ---- phase 1a: chunks 0..3 pipelined (slack for peer skew) ----
        LDX(pa, 0); LDX(pb, 1);
        FMA1(pa, 0); LDX(pa, 2);
        FMA1(pb, 1); LDX(pb, 3);
        FMA1(pa, 2); LDX(pa, 4);
        FMA1(pb, 3); LDX(pb, 5);

        if (s > 0) {
            // ---- wait for group peers: AGENT-scope poll (placement-independent) ----
            if (tid == 0) {
                const unsigned tgt = 8u * (unsigned)s;
                unsigned it = 0;
                while (__hip_atomic_load(gcnt, __ATOMIC_RELAXED,
                                         __HIP_MEMORY_SCOPE_AGENT) < tgt) {
                    if (++it > (1u << 20)) break;   // hang-safety escape
                }
            }
            __syncthreads();   // cheap: nothing significant outstanding now

            // ---- issue h staging DMA (device-coherent); drained after 1b ----
            {
                const __bf16* src = ((s & 1) ? Hb1 : Hb0) + hrow;
                __bf16* dst = hbuf + wave * 512;
#pragma unroll
                for (int c = 0; c < NC2; ++c)
                    GLLD_SYS(src + c * 32, dst + c * 2048);
            }
        }

        // ---- phase 1b: chunks 4..9 pipelined (hides the h-DMA round trip) ----
        FMA1(pa, 4); LDX(pa, 6);
        FMA1(pb, 5); LDX(pb, 7);
        FMA1(pa, 6); LDX(pa, 8);
        FMA1(pb, 7); LDX(pb, 9);
        FMA1(pa, 8);
        FMA1(pb, 9);

        if (s > 0) {
            __syncthreads();   // vmcnt(0): drains ONLY the h DMA (X not issued yet)

            // ---- issue X(s+1) now; drains at the post-epilogue barrier,
            //      overlapped with phase 2 + epilogue + publish ack ----
            if (s < S_ - 1) XDMA(s + 1);

            // ---- phase 2: h @ Whh^T, 16 chunks, 2-deep pipelined ----
            LDH(pa, 0); LDH(pb, 1);
#pragma unroll
            for (int cc = 0; cc < 7; ++cc) {
                FMA2(pa, 2 * cc);     LDH(pa, 2 * cc + 2);
                FMA2(pb, 2 * cc + 1); LDH(pb, 2 * cc + 3);
            }
            FMA2(pa, 14);
            FMA2(pb, 15);
        }
        // s == 0: h = 0, so gh = bhh exactly — already folded into b_r/b_z/b_nh.

        // ---- epilogue: GRU cell, reg-resident h & masked sum, publish bf16 h ----
        {
            __bf16* hb_w = (s & 1) ? Hb0 : Hb1;
            // h(63) is never consumed (only ssum survives) -> skip its publish.
            const bool store_lane = ((lane & 1) == 0) && (s < S_ - 1);
#pragma unroll
            for (int mt = 0; mt < 4; ++mt) {
#pragma unroll
                for (int reg = 0; reg < 4; ++reg) {
                    const int i = mt * 4 + reg;
                    const float r = 1.f / (1.f + __expf(-(acc[mt][0][reg] + b_r)));
                    const float z = 1.f / (1.f + __expf(-(acc[mt][1][reg] + b_z)));
                    const float nv = acc[mt][2][reg] + b_ni + r * (acc[mt][3][reg] + b_nh);
                    const float n = 2.f / (1.f + __expf(-2.f * nv)) - 1.f;   // tanh
                    const float hnew = (1.f - z) * n + z * hreg[i];
                    hreg[i] = hnew;
                    if (((lenp[mt] >> (reg * 8)) & 255u) > (unsigned)s) ssum[i] += hnew;
                    __bf16 hb16 = (__bf16)hnew;
                    unsigned short myb = __builtin_bit_cast(unsigned short, hb16);
                    unsigned ob = (unsigned)__shfl_xor((int)(unsigned)myb, 1, 64);
                    if (store_lane) {
                        const int b = b0 + mt * 16 + (lane >> 4) * 4 + reg;
                        // AGENT-scope store: lands at the device coherence point,
                        // acked before the post-epilogue __syncthreads releases.
                        __hip_atomic_store(
                            (unsigned*)(hb_w + (size_t)(dir * B_ + b) * H_ + jcol),
                            (unsigned)myb | (ob << 16),
                            __ATOMIC_RELAXED, __HIP_MEMORY_SCOPE_AGENT);
                    }
                }
            }
        }
        __syncthreads();   // vmcnt(0): publish stores acked; X(s+1) drained
        if (tid == 0 && s < S_ - 1)
            __hip_atomic_fetch_add(gcnt, 1u, __ATOMIC_RELAXED,
                                   __HIP_MEMORY_SCOPE_AGENT);
    }

#undef LDX
#undef LDH
#undef FMA1
#undef FMA2
#undef XDMA

    // write masked sums (consumed by next kernel; dispatch-boundary flush)
#pragma unroll
    for (int mt = 0; mt < 4; ++mt)
#pragma unroll
        for (int reg = 0; reg < 4; ++reg) {
            const int b = b0 + mt * 16 + (lane >> 4) * 4 + reg;
            Ssum[(size_t)(dir * B_ + b) * H_ + jcol] = ssum[mt * 4 + reg];
        }
}

// ---------------- head ----------------
__global__ __launch_bounds__(128) void avg_prep(const float* __restrict__ Ssum,
                                                const int* __restrict__ lens,
                                                __bf16* __restrict__ Avg) {
    int b = blockIdx.x, t = threadIdx.x;
    float inv = 0.5f / (float)lens[b];
    float4 a = *(const float4*)(Ssum + (size_t)b * H_ + t * 4);
    float4 c = *(const float4*)(Ssum + (size_t)(B_ + b) * H_ + t * 4);
    __bf16* dst = Avg + (size_t)b * H_ + t * 4;
    dst[0] = (__bf16)((a.x + c.x) * inv);
    dst[1] = (__bf16)((a.y + c.y) * inv);
    dst[2] = (__bf16)((a.z + c.z) * inv);
    dst[3] = (__bf16)((a.w + c.w) * inv);
}

// Avg[1024x512] @ Wcat[256x512]^T -> mu/sigma planes of out
__global__ __launch_bounds__(256) void head_gemm(
    const __bf16* __restrict__ Avg, const __bf16* __restrict__ Wcat,
    const float* __restrict__ b_mu, const float* __restrict__ b_sig,
    float* __restrict__ out)
{
    __shared__ __align__(16) __bf16 abuf[16 * 2048];   // 64 KB static
    const int bid = blockIdx.x;                        // 64
    const int mb = bid >> 2, jb = bid & 3;
    const int tid = threadIdx.x, wave = tid >> 6, lane = tid & 63;
    const int srow = tid >> 2, scol = (tid & 3) * 8;
    const __bf16* asrc = Avg + (size_t)(mb * 64 + srow) * H_ + scol;
    {
        __bf16* dst = abuf + wave * 512;
#pragma unroll
        for (int c = 0; c < 16; ++c) GLLD(asrc + c * 32, dst + c * 2048);
    }
    __syncthreads();
    const int j = jb * 64 + wave * 16 + (lane & 15);   // 0..255
    const int kq8 = (lane >> 4) * 8;
    const __bf16* wp = Wcat + (size_t)j * H_ + kq8;
    const int aoff = (lane & 15) * 32 + kq8;
    f32x4 acc[4];
#pragma unroll
    for (int mt = 0; mt < 4; ++mt) acc[mt] = (f32x4){0.f, 0.f, 0.f, 0.f};
#pragma unroll
    for (int c = 0; c < 16; ++c) {
        bf16x8 wf = *(const bf16x8*)(wp + c * 32);
#pragma unroll
        for (int mt = 0; mt < 4; ++mt) {
            bf16x8 af = *(const bf16x8*)(abuf + c * 2048 + aoff + mt * 512);
            acc[mt] = MFMA(af, wf, acc[mt]);
        }
    }
    const int gate = j >> 7, z = j & 127;
    const float bias = gate ? b_sig[z] : b_mu[z];
#pragma unroll
    for (int mt = 0; mt < 4; ++mt)
#pragma unroll
        for (int reg = 0; reg < 4; ++reg) {
            const int b = mb * 64 + mt * 16 + (lane >> 4) * 4 + reg;
            float v = acc[mt][reg] + bias;
            v = v >= 0.f ? v : 0.2f * v;
            if (gate) v = __expf(v);
            out[(size_t)(1 + gate) * B_ * Z_ + (size_t)b * Z_ + z] = v;
        }
}

__global__ __launch_bounds__(256) void final_k(const float* __restrict__ eps,
                                               float* __restrict__ out) {
    int i = blockIdx.x * 256 + threadIdx.x;    // 131072
    out[i] = eps[i] * out[2 * B_ * Z_ + i] + out[B_ * Z_ + i];
}

extern "C" void kernel_launch(void* const* d_in, const int* in_sizes, int n_in,
                              void* d_out, int out_size, void* d_ws, size_t ws_size,
                              hipStream_t stream) {
    const float* text  = (const float*)d_in[0];
    const int*   lens  = (const int*)  d_in[1];
    const float* Wih_f = (const float*)d_in[2];
    const float* Whh_f = (const float*)d_in[3];
    const float* bih_f = (const float*)d_in[4];
    const float* bhh_f = (const float*)d_in[5];
    const float* Wih_b = (const float*)d_in[6];
    const float* Whh_b = (const float*)d_in[7];
    const float* bih_b = (const float*)d_in[8];
    const float* bhh_b = (const float*)d_in[9];
    const float* W_mu  = (const float*)d_in[10];
    const float* b_mu  = (const float*)d_in[11];
    const float* W_sig = (const float*)d_in[12];
    const float* b_sig = (const float*)d_in[13];
    const float* eps   = (const float*)d_in[14];
    float* out = (float*)d_out;

    char* ws = (char*)d_ws;
    __bf16* Xbf  = (__bf16*)(ws);                   // 41943040
    __bf16* Wk1  = (__bf16*)(ws + 41943040);        //  1966080
    __bf16* Wk2  = (__bf16*)(ws + 43909120);        //  3145728
    __bf16* Hb0  = (__bf16*)(ws + 47054848);        //  2097152
    __bf16* Hb1  = (__bf16*)(ws + 49152000);        //  2097152
    float*  Ssum = (float*) (ws + 51249152);        //  4194304
    __bf16* Avg  = (__bf16*)(ws + 55443456);        //  1048576
    __bf16* Wcat = (__bf16*)(ws + 56492032);        //   262144
    unsigned* cntp = (unsigned*)(ws + 56754176);    //     8192 (32 groups x 256 B)
    // total 56762368 bytes

    prep_cnt<<<8, 256, 0, stream>>>(cntp);
    prep_text<<<B_ * S_, 320, 0, stream>>>(text, Xbf);
    prep_w<<<10496, 256, 0, stream>>>(Wih_f, Whh_f, Wih_b, Whh_b, W_mu, W_sig,
                                      Wk1, Wk2, Wcat);

    void* args[] = { (void*)&Xbf, (void*)&Wk1, (void*)&Wk2,
                     (void*)&bih_f, (void*)&bhh_f, (void*)&bih_b, (void*)&bhh_b,
                     (void*)&lens, (void*)&Hb0, (void*)&Hb1,
                     (void*)&Ssum, (void*)&cntp };
    hipError_t ce = hipLaunchCooperativeKernel((void*)gru_persist, dim3(256),
                                               dim3(256), args, 0, stream);
    if (ce != hipSuccess) {
        gru_persist<<<256, 256, 0, stream>>>(Xbf, Wk1, Wk2,
                                             bih_f, bhh_f, bih_b, bhh_b,
                                             lens, Hb0, Hb1, Ssum, cntp);
    }

    avg_prep<<<B_, 128, 0, stream>>>(Ssum, lens, Avg);
    head_gemm<<<64, 256, 0, stream>>>(Avg, Wcat, b_mu, b_sig, out);
    final_k<<<512, 256, 0, stream>>>(eps, out);
}